// Round 5
// baseline (107.959 us; speedup 1.0000x reference)
//
#include <hip/hip_runtime.h>

// SpatialIndependentDistribution, round 5: single kernel, no staging.
// 64 pixels/wave, chained MFMA 16x16x16 f16. A-fragments loaded directly from
// global as per-lane dwordx4 (the fragment's 4 elements are contiguous in the
// row-major weight matrices); biases as quad-indexed float4; b3 via s_load.
// Head (n1 net on zeros) = 2 MFMAs once per wave (B operand pixel-independent).

#define NEG_HALF_LOG_2PI -0.91893853320467274f

typedef _Float16 f16x4 __attribute__((ext_vector_type(4)));
typedef __fp16   hf2   __attribute__((ext_vector_type(2)));
typedef float    f32x4 __attribute__((ext_vector_type(4)));

__device__ inline f16x4 pack_f16(f32x4 v) {
    hf2 p0 = __builtin_amdgcn_cvt_pkrtz(v[0], v[1]);
    hf2 p1 = __builtin_amdgcn_cvt_pkrtz(v[2], v[3]);
    f16x4 r;
    __builtin_memcpy(&r, &p0, 4);
    __builtin_memcpy((char*)&r + 4, &p1, 4);
    return r;
}

__device__ inline f16x4 relu_pack(f32x4 d) {
    hf2 p0 = __builtin_amdgcn_cvt_pkrtz(fmaxf(d[0], 0.0f), fmaxf(d[1], 0.0f));
    hf2 p1 = __builtin_amdgcn_cvt_pkrtz(fmaxf(d[2], 0.0f), fmaxf(d[3], 0.0f));
    f16x4 r;
    __builtin_memcpy(&r, &p0, 4);
    __builtin_memcpy((char*)&r + 4, &p1, 4);
    return r;
}

__global__ __launch_bounds__(256, 4) void spatial_main(
    const float* __restrict__ samples,   // [64,16,64,64]
    const float* __restrict__ n1_b1,     // [16]
    const float* __restrict__ n1_w2,     // [16,16]
    const float* __restrict__ n1_b2,     // [16]
    const float* __restrict__ n1_w3,     // [2,16]
    const float* __restrict__ n1_b3,     // [2]
    const float* __restrict__ w1,        // [15,16,16] zero-padded triangular
    const float* __restrict__ b1,        // [15,16]
    const float* __restrict__ w2,        // [15,16,16]
    const float* __restrict__ b2,        // [15,16]
    const float* __restrict__ w3,        // [15,2,16]
    const float* __restrict__ b3,        // [15,2]
    float* __restrict__ out)             // [64,64,64]
{
    const int tid   = threadIdx.x;
    const int lane  = tid & 63;
    const int wv    = tid >> 6;
    const int q     = lane >> 4;          // quad 0..3
    const int col   = lane & 15;
    const int row   = lane & 15;          // A-frag row
    const int q4    = q << 2;
    const int roff  = row * 16 + q4;      // A-frag: 4 contiguous elems at [row][4q]
    const int r4    = row & 3;
    const int w3off = ((row & 1) << 4) + q4;   // replicate W3 rows into {0,1} mod 4
    const bool w3on = r4 < 2;

    const int pbase = blockIdx.x * 256 + wv * 64;       // wave's first pixel
    const int b     = pbase >> 12;
    const int hw    = pbase & 4095;
    const float* xw = samples + ((size_t)b << 16) + hw; // + ch*4096 + 0..63

    // B-fragments: chain ch covers pixels pbase+16ch..+15; lane holds ch 4q..4q+3
    f16x4 bx[4];
    #pragma unroll
    for (int ch = 0; ch < 4; ++ch)
        #pragma unroll
        for (int i = 0; i < 4; ++i)
            bx[ch][i] = (_Float16)xw[((q4 + i) << 12) + (ch << 4) + col];

    // ---- head: n1 net on zero input; B operand is pixel-independent ----
    float accz, accl;
    {
        f32x4 c1h = *(const f32x4*)(n1_b1 + q4);        // C-layout == B-layout
        f16x4 h1h = relu_pack(c1h);
        f16x4 a2h = pack_f16(*(const f32x4*)(n1_w2 + roff));
        f32x4 c2h = *(const f32x4*)(n1_b2 + q4);
        f32x4 d2h = __builtin_amdgcn_mfma_f32_16x16x16f16(a2h, h1h, c2h, 0, 0, 0);
        f16x4 h2h = relu_pack(d2h);
        f32x4 v3h = *(const f32x4*)(n1_w3 + w3off);
        if (!w3on) { v3h[0] = 0.f; v3h[1] = 0.f; v3h[2] = 0.f; v3h[3] = 0.f; }
        f16x4 a3h = pack_f16(v3h);
        f32x4 c3h = {n1_b3[0], n1_b3[1], 0.0f, 0.0f};
        f32x4 d3h = __builtin_amdgcn_mfma_f32_16x16x16f16(a3h, h2h, c3h, 0, 0, 0);
        // every lane holds (loc0, ls0) in regs 0,1 (replicated rows/cols)
        float x0 = xw[lane];
        float ls = d3h[1];
        float z0 = (x0 - d3h[0]) * __expf(-ls);
        accz = z0 * z0;
        accl = ls;
    }

    // ---- 15 autoregressive steps ----
    #pragma unroll
    for (int s = 0; s < 15; ++s) {
        f16x4 a1 = pack_f16(*(const f32x4*)(w1 + s * 256 + roff));
        f16x4 a2 = pack_f16(*(const f32x4*)(w2 + s * 256 + roff));
        f32x4 v3 = *(const f32x4*)(w3 + s * 32 + w3off);
        if (!w3on) { v3[0] = 0.f; v3[1] = 0.f; v3[2] = 0.f; v3[3] = 0.f; }
        f16x4 a3 = pack_f16(v3);
        f32x4 c1 = *(const f32x4*)(b1 + s * 16 + q4);
        f32x4 c2 = *(const f32x4*)(b2 + s * 16 + q4);
        f32x4 c3 = {b3[s * 2 + 0], b3[s * 2 + 1], 0.0f, 0.0f};   // uniform -> s_load

        float loc_q[4], ls_q[4];
        #pragma unroll
        for (int ch = 0; ch < 4; ++ch) {
            f32x4 d1 = __builtin_amdgcn_mfma_f32_16x16x16f16(a1, bx[ch], c1, 0, 0, 0);
            f16x4 h1 = relu_pack(d1);
            f32x4 d2 = __builtin_amdgcn_mfma_f32_16x16x16f16(a2, h1, c2, 0, 0, 0);
            f16x4 h2 = relu_pack(d2);
            f32x4 d3 = __builtin_amdgcn_mfma_f32_16x16x16f16(a3, h2, c3, 0, 0, 0);
            loc_q[ch] = d3[0];
            ls_q[ch]  = d3[1];
        }
        // quad q takes chain q's epilogue -> 1 coalesced xn load per step
        float loc = q == 0 ? loc_q[0] : q == 1 ? loc_q[1] : q == 2 ? loc_q[2] : loc_q[3];
        float ls  = q == 0 ? ls_q[0]  : q == 1 ? ls_q[1]  : q == 2 ? ls_q[2]  : ls_q[3];
        float xn  = xw[((s + 1) << 12) + lane];      // channel s+1, pixel pbase+lane
        float z   = (xn - loc) * __expf(-ls);
        accz = fmaf(z, z, accz);
        accl += ls;
    }

    // out = -0.5*accz - accl + 16*(-0.5*log(2pi)); all 64 lanes write coalesced
    out[pbase + lane] = fmaf(-0.5f, accz, 16.0f * NEG_HALF_LOG_2PI - accl);
}

extern "C" void kernel_launch(void* const* d_in, const int* in_sizes, int n_in,
                              void* d_out, int out_size, void* d_ws, size_t ws_size,
                              hipStream_t stream) {
    const float* samples = (const float*)d_in[0];
    // d_in[1] = n1_w1 unused (first-channel input is zeros)
    const float* n1_b1   = (const float*)d_in[2];
    const float* n1_w2   = (const float*)d_in[3];
    const float* n1_b2   = (const float*)d_in[4];
    const float* n1_w3   = (const float*)d_in[5];
    const float* n1_b3   = (const float*)d_in[6];
    const float* w1      = (const float*)d_in[7];
    const float* b1      = (const float*)d_in[8];
    const float* w2      = (const float*)d_in[9];
    const float* b2      = (const float*)d_in[10];
    const float* w3      = (const float*)d_in[11];
    const float* b3      = (const float*)d_in[12];
    float* out = (float*)d_out;

    // 262144 pixels / 64 per wave / 4 waves per block = 1024 blocks
    spatial_main<<<dim3(1024), dim3(256), 0, stream>>>(
        samples, n1_b1, n1_w2, n1_b2, n1_w3, n1_b3,
        w1, b1, w2, b2, w3, b3, out);
}

// Round 7
// 101.987 us; speedup vs baseline: 1.0586x; 1.0586x over previous
//
#include <hip/hip_runtime.h>

// SpatialIndependentDistribution, round 7: LDS-staged fragments (R6 + bias-staging fix).
// Stage pre-swizzled f16 A-fragments + biases into LDS once per block with
// coalesced float4 loads (cheap shift-only indexing), then 15 chained MFMA
// steps reading frags via ds_read_b64 (consecutive-lane, conflict-free).
// 64 pixels/wave, quad-parallel epilogue, coalesced xn loads + output store.

#define NEG_HALF_LOG_2PI -0.91893853320467274f

typedef _Float16 f16x4 __attribute__((ext_vector_type(4)));
typedef __fp16   hf2   __attribute__((ext_vector_type(2)));
typedef float    f32x4 __attribute__((ext_vector_type(4)));

__device__ inline f16x4 pack_f16(f32x4 v) {
    hf2 p0 = __builtin_amdgcn_cvt_pkrtz(v[0], v[1]);
    hf2 p1 = __builtin_amdgcn_cvt_pkrtz(v[2], v[3]);
    f16x4 r;
    __builtin_memcpy(&r, &p0, 4);
    __builtin_memcpy((char*)&r + 4, &p1, 4);
    return r;
}

__device__ inline f16x4 relu_pack(f32x4 d) {
    hf2 p0 = __builtin_amdgcn_cvt_pkrtz(fmaxf(d[0], 0.0f), fmaxf(d[1], 0.0f));
    hf2 p1 = __builtin_amdgcn_cvt_pkrtz(fmaxf(d[2], 0.0f), fmaxf(d[3], 0.0f));
    f16x4 r;
    __builtin_memcpy(&r, &p0, 4);
    __builtin_memcpy((char*)&r + 4, &p1, 4);
    return r;
}

__global__ __launch_bounds__(256, 4) void spatial_main(
    const float* __restrict__ samples,   // [64,16,64,64]
    const float* __restrict__ n1_b1,     // [16]
    const float* __restrict__ n1_w2,     // [16,16]
    const float* __restrict__ n1_b2,     // [16]
    const float* __restrict__ n1_w3,     // [2,16]
    const float* __restrict__ n1_b3,     // [2]
    const float* __restrict__ w1,        // [15,16,16] zero-padded triangular
    const float* __restrict__ b1,        // [15,16]
    const float* __restrict__ w2,        // [15,16,16]
    const float* __restrict__ b2,        // [15,16]
    const float* __restrict__ w3,        // [15,2,16]
    const float* __restrict__ b3,        // [15,2]
    float* __restrict__ out)             // [64,64,64]
{
    // A-fragments: fA[sl*256 + lane*4 + i] = W_sl[lane&15][4*(lane>>4)+i], f16
    __shared__ _Float16 fA[45 * 256];    // 23040 B
    __shared__ float    fC[15 * 2 * 16]; // 1920 B  (b1,b2 as MFMA C operands)

    const int tid   = threadIdx.x;
    const int lane  = tid & 63;
    const int wv    = tid >> 6;
    const int q     = lane >> 4;          // quad 0..3
    const int col   = lane & 15;
    const int lane4 = lane << 2;
    const int q4    = q << 2;
    const int roff  = col * 16 + q4;      // head A-frag: [row][4q], contiguous

    // ---- stage w1/w2 fragments: 30 matrices x 64 float4, coalesced ----
    for (int j = tid; j < 30 * 64; j += 256) {
        int m   = j >> 6;                 // matrix 0..29
        int rem = j & 63;
        int r   = rem >> 2;               // row 0..15
        int c   = rem & 3;                // float4 within row
        const float* src = (m < 15) ? (w1 + m * 256) : (w2 + (m - 15) * 256);
        f32x4 v = *(const f32x4*)(src + r * 16 + (c << 2));
        int sl = (m < 15) ? (m * 3) : ((m - 15) * 3 + 1);
        *(f16x4*)&fA[sl * 256 + (((c << 4) + r) << 2)] = pack_f16(v);
    }
    // ---- stage w3 fragments (rows replicated into {0,1} mod 4, else 0) ----
    for (int j = tid; j < 15 * 64; j += 256) {
        int s  = j >> 6;
        int ln = j & 63;
        int r  = ln & 15;
        int qq = ln >> 4;
        f32x4 v = {0.f, 0.f, 0.f, 0.f};
        if ((r & 3) < 2) v = *(const f32x4*)(w3 + s * 32 + ((r & 1) << 4) + (qq << 2));
        *(f16x4*)&fA[(s * 3 + 2) * 256 + (ln << 2)] = pack_f16(v);
    }
    // ---- stage b1/b2 (stride loop: 480 entries, 256 threads!) ----
    for (int j = tid; j < 15 * 2 * 16; j += 256) {
        int s = j >> 5, layer = (j >> 4) & 1, o = j & 15;
        fC[j] = layer ? b2[s * 16 + o] : b1[s * 16 + o];
    }

    // ---- pixel loads + head (independent of LDS, overlaps staging) ----
    const int pbase = blockIdx.x * 256 + wv * 64;       // wave's first pixel
    const int b     = pbase >> 12;
    const int hw    = pbase & 4095;
    const float* xw = samples + ((size_t)b << 16) + hw; // + ch*4096 + 0..63

    f16x4 bx[4];
    #pragma unroll
    for (int ch = 0; ch < 4; ++ch)
        #pragma unroll
        for (int i = 0; i < 4; ++i)
            bx[ch][i] = (_Float16)xw[((q4 + i) << 12) + (ch << 4) + col];

    float accz, accl;
    {   // head: n1 net on zero input; B operand pixel-independent; 2 MFMAs
        f32x4 c1h = *(const f32x4*)(n1_b1 + q4);        // C-layout == B-layout
        f16x4 h1h = relu_pack(c1h);
        f16x4 a2h = pack_f16(*(const f32x4*)(n1_w2 + roff));
        f32x4 c2h = *(const f32x4*)(n1_b2 + q4);
        f32x4 d2h = __builtin_amdgcn_mfma_f32_16x16x16f16(a2h, h1h, c2h, 0, 0, 0);
        f16x4 h2h = relu_pack(d2h);
        f32x4 v3h = {0.f, 0.f, 0.f, 0.f};
        if ((col & 3) < 2) v3h = *(const f32x4*)(n1_w3 + ((col & 1) << 4) + q4);
        f16x4 a3h = pack_f16(v3h);
        f32x4 c3h = {n1_b3[0], n1_b3[1], 0.0f, 0.0f};
        f32x4 d3h = __builtin_amdgcn_mfma_f32_16x16x16f16(a3h, h2h, c3h, 0, 0, 0);
        float x0 = xw[lane];
        float ls = d3h[1];
        float z0 = (x0 - d3h[0]) * __expf(-ls);
        accz = z0 * z0;
        accl = ls;
    }

    __syncthreads();

    // ---- 15 autoregressive steps, frags from LDS ----
    #pragma unroll
    for (int s = 0; s < 15; ++s) {
        f16x4 a1 = *(const f16x4*)&fA[(s * 3 + 0) * 256 + lane4];  // ds_read_b64
        f16x4 a2 = *(const f16x4*)&fA[(s * 3 + 1) * 256 + lane4];
        f16x4 a3 = *(const f16x4*)&fA[(s * 3 + 2) * 256 + lane4];
        f32x4 c1 = *(const f32x4*)&fC[(s * 2 + 0) * 16 + q4];
        f32x4 c2 = *(const f32x4*)&fC[(s * 2 + 1) * 16 + q4];
        f32x4 c3 = {b3[s * 2 + 0], b3[s * 2 + 1], 0.0f, 0.0f};     // s_load

        float loc_q[4], ls_q[4];
        #pragma unroll
        for (int ch = 0; ch < 4; ++ch) {
            f32x4 d1 = __builtin_amdgcn_mfma_f32_16x16x16f16(a1, bx[ch], c1, 0, 0, 0);
            f16x4 h1 = relu_pack(d1);
            f32x4 d2 = __builtin_amdgcn_mfma_f32_16x16x16f16(a2, h1, c2, 0, 0, 0);
            f16x4 h2 = relu_pack(d2);
            f32x4 d3 = __builtin_amdgcn_mfma_f32_16x16x16f16(a3, h2, c3, 0, 0, 0);
            loc_q[ch] = d3[0];
            ls_q[ch]  = d3[1];
        }
        // quad q takes chain q's epilogue -> 1 coalesced xn load per step
        float loc = q == 0 ? loc_q[0] : q == 1 ? loc_q[1] : q == 2 ? loc_q[2] : loc_q[3];
        float ls  = q == 0 ? ls_q[0]  : q == 1 ? ls_q[1]  : q == 2 ? ls_q[2]  : ls_q[3];
        float xn  = xw[((s + 1) << 12) + lane];      // channel s+1, pixel pbase+lane
        float z   = (xn - loc) * __expf(-ls);
        accz = fmaf(z, z, accz);
        accl += ls;
    }

    // out = -0.5*accz - accl + 16*(-0.5*log(2pi)); all 64 lanes write coalesced
    out[pbase + lane] = fmaf(-0.5f, accz, 16.0f * NEG_HALF_LOG_2PI - accl);
}

extern "C" void kernel_launch(void* const* d_in, const int* in_sizes, int n_in,
                              void* d_out, int out_size, void* d_ws, size_t ws_size,
                              hipStream_t stream) {
    const float* samples = (const float*)d_in[0];
    // d_in[1] = n1_w1 unused (first-channel input is zeros)
    const float* n1_b1   = (const float*)d_in[2];
    const float* n1_w2   = (const float*)d_in[3];
    const float* n1_b2   = (const float*)d_in[4];
    const float* n1_w3   = (const float*)d_in[5];
    const float* n1_b3   = (const float*)d_in[6];
    const float* w1      = (const float*)d_in[7];
    const float* b1      = (const float*)d_in[8];
    const float* w2      = (const float*)d_in[9];
    const float* b2      = (const float*)d_in[10];
    const float* w3      = (const float*)d_in[11];
    const float* b3      = (const float*)d_in[12];
    float* out = (float*)d_out;

    // 262144 pixels / 64 per wave / 4 waves per block = 1024 blocks
    spatial_main<<<dim3(1024), dim3(256), 0, stream>>>(
        samples, n1_b1, n1_w2, n1_b2, n1_w3, n1_b3,
        w1, b1, w2, b2, w3, b3, out);
}